// Round 8
// baseline (134.724 us; speedup 1.0000x reference)
//
#include <hip/hip_runtime.h>
#include <hip/hip_fp16.h>

typedef _Float16 half8 __attribute__((ext_vector_type(8)));
typedef _Float16 half4v __attribute__((ext_vector_type(4)));
typedef __attribute__((ext_vector_type(4))) float f32x4;

#define OUT_ELEMS 8388608

// ws layout (bytes):
// 0      counts int[1024]        (zeroed by prep block 0)
// 4096   loss   float            (zeroed by prep)
// 8192   sq     float[1024]
// 16384  chs    ushort[1024*256] (fp16 of 1024*cb, ROW-MAJOR)
//
// B is NOT staged through LDS. The mfma_f32_16x16x32_f16 B-fragment layout
// (lane = code(m) + 16*kquarter(q), 16B/lane) maps directly onto row-major
// chs: lane(m,q) reads chs + code*512B + ks*64B + q*16B. The 4 q-lanes of a
// code cover one full 64B line -> 16 complete lines per wave instruction.
// chs (512KB) is L2-resident -> the main loop has NO LDS ops, NO barriers.

// ---- prep: zero accumulators + codebook -> fp16*1024 + ||c||^2 ----
__global__ __launch_bounds__(256) void prep_kernel(const float* __restrict__ cb,
        unsigned short* __restrict__ chs, float* __restrict__ sq,
        int* __restrict__ counts, float* __restrict__ loss) {
    const int t = threadIdx.x;
    if (blockIdx.x == 0) {
        ((int4*)counts)[t] = make_int4(0, 0, 0, 0);
        if (t == 0) *loss = 0.f;
    }
    const int row = blockIdx.x * 16 + (t >> 4);   // code index 0..1023
    const int d0 = (t & 15) * 16;
    const float* src = cb + row * 256 + d0;
    half8 h0, h1;
    float s = 0.f;
#pragma unroll
    for (int i = 0; i < 16; ++i) {
        const float v = src[i];
        s += v * v;
        const _Float16 h = (_Float16)(v * 1024.f);
        if (i < 8) h0[i] = h; else h1[i - 8] = h;
    }
    *(half8*)(chs + row * 256 + d0)     = h0;
    *(half8*)(chs + row * 256 + d0 + 8) = h1;
#pragma unroll
    for (int off = 1; off < 16; off <<= 1) s += __shfl_xor(s, off);
    if ((t & 15) == 0) sq[row] = s;
}

// ---- fused vq: grid 256 (1/CU), 512 thr = 8 waves = 4 code-groups x 2 row-groups.
// M=128 rows/block. Main loop: B streamed global->VGPR in MFMA frag layout.
// No LDS, no barriers, no inline asm in the loop -- waves free-run and the
// 2 waves/SIMD hide each other's L2 latency.
__global__ __launch_bounds__(512, 2) void vq_kernel(
    const float* __restrict__ x, const float* __restrict__ cb,
    const unsigned short* __restrict__ chs, const float* __restrict__ sq,
    int* __restrict__ counts, float* __restrict__ loss_accum,
    float* __restrict__ out)
{
    __shared__ __align__(16) unsigned char Arena[65536]; // XL(64K) -> Q(33K)
    __shared__ float mv[4][128];
    __shared__ int   mk[4][128];
    __shared__ float xsqL[128];
    __shared__ int   codeL[128];
    __shared__ float wsum[2];

    const int t = threadIdx.x;
    const int lane = t & 63;
    const int w  = t >> 6;
    const int wg = w >> 1;            // code group 0..3 (256 codes each)
    const int wl = w & 1;             // row group 0..1 (64 rows each)
    const int m = lane & 15;
    const int q = lane >> 4;
    const int kb = wg << 8;
    const int rowb = wl << 6;
    const int bid = blockIdx.x;
    const int batch = bid >> 3;
    const int hwb = (bid & 7) << 7;   // 128 hw rows per block

    // ---- x staging: fp32 [c][hw] (coalesced) -> fp16 [hw:128][c:256] LDS, swizzled
    // 8B-group swizzle e(hw) = ((hw&7) ^ ((hw>>3)&7)) << 1 (even keeps 16B pairs).
    unsigned short* XL = (unsigned short*)Arena;
    {
        const float* xg = x + (size_t)batch * 262144 + hwb;
#pragma unroll
        for (int p = 0; p < 4; ++p) {
            const int id = p * 512 + t;
            const int c4 = id >> 5;       // 0..63 (c-group of 4)
            const int hw4 = id & 31;      // 0..31 (hw-group of 4)
            const float* s0 = xg + (size_t)(c4 * 4) * 1024 + hw4 * 4;
            const f32x4 v0 = *(const f32x4*)(s0);
            const f32x4 v1 = *(const f32x4*)(s0 + 1024);
            const f32x4 v2 = *(const f32x4*)(s0 + 2048);
            const f32x4 v3 = *(const f32x4*)(s0 + 3072);
#pragma unroll
            for (int j = 0; j < 4; ++j) {
                const int hw = hw4 * 4 + j;
                const int e = (((hw & 7) ^ ((hw >> 3) & 7)) << 1);
                half4v hv;
                hv[0] = (_Float16)v0[j];
                hv[1] = (_Float16)v1[j];
                hv[2] = (_Float16)v2[j];
                hv[3] = (_Float16)v3[j];
                *(half4v*)(XL + hw * 256 + ((c4 ^ e) << 2)) = hv;
            }
        }
    }
    __syncthreads();

    // ---- A frags from LDS (conflict-free b128); fused ||x||^2 (fp16 path)
    half8 Ah[4][8];
#pragma unroll
    for (int f = 0; f < 4; ++f) {
        const int hw = rowb + f * 16 + m;
        const unsigned short* row = XL + hw * 256;
        const int e = (((hw & 7) ^ ((hw >> 3) & 7)) << 1);
        float xs = 0.f;
#pragma unroll
        for (int ks = 0; ks < 8; ++ks) {
            const half8 a = *(const half8*)(row + (((8 * ks + 2 * q) ^ e) << 2));
            Ah[f][ks] = a;
#pragma unroll
            for (int j = 0; j < 8; ++j) { const float fv = (float)a[j]; xs = fmaf(fv, fv, xs); }
        }
        xs += __shfl_xor(xs, 16);
        xs += __shfl_xor(xs, 32);
        if (wg == 0 && q == 0) xsqL[hw] = xs;
    }
    // NO barrier here: XL is only overwritten by gather, which is after two
    // later barriers. Waves enter the loop independently.

    float bestv[4][4];
    int   bestk[4][4];
#pragma unroll
    for (int f = 0; f < 4; ++f)
#pragma unroll
        for (int r = 0; r < 4; ++r) { bestv[f][r] = 3.4e38f; bestk[f][r] = 0; }

    float sc2 = sq[kb + m];           // stage-0 ||c||^2

    // per-lane B base: code row (kb + m), k-offset q*16B. Frag values are
    // bit-identical to the LDS path (same fp16 data, same MFMA order).
    const unsigned short* bgl = chs + (size_t)(kb + m) * 256 + q * 8;

    for (int s = 0; s < 16; ++s) {    // 16 codes per step per group
        float sqn = 0.f;
        if (s + 1 < 16) sqn = sq[kb + (s + 1) * 16 + m];
        half8 Bf[8];
        const unsigned short* bp = bgl + s * 4096;   // s*16 codes * 256 hw
#pragma unroll
        for (int ks = 0; ks < 8; ++ks)
            Bf[ks] = *(const half8*)(bp + ks * 32);  // 64B chunk ks of the row
        f32x4 a0 = {0.f,0.f,0.f,0.f}, a1 = {0.f,0.f,0.f,0.f};
        f32x4 a2 = {0.f,0.f,0.f,0.f}, a3 = {0.f,0.f,0.f,0.f};
#pragma unroll
        for (int ks = 0; ks < 8; ++ks) {
            a0 = __builtin_amdgcn_mfma_f32_16x16x32_f16(Ah[0][ks], Bf[ks], a0, 0, 0, 0);
            a1 = __builtin_amdgcn_mfma_f32_16x16x32_f16(Ah[1][ks], Bf[ks], a1, 0, 0, 0);
            a2 = __builtin_amdgcn_mfma_f32_16x16x32_f16(Ah[2][ks], Bf[ks], a2, 0, 0, 0);
            a3 = __builtin_amdgcn_mfma_f32_16x16x32_f16(Ah[3][ks], Bf[ks], a3, 0, 0, 0);
        }
        const int code = kb + s * 16 + m;
#pragma unroll
        for (int f = 0; f < 4; ++f) {
            const f32x4 a = (f == 0) ? a0 : (f == 1) ? a1 : (f == 2) ? a2 : a3;
#pragma unroll
            for (int r = 0; r < 4; ++r) {
                const float d0v = fmaf(-0.001953125f, a[r], sc2);  // -2/1024 undoes B scale
                if (d0v < bestv[f][r]) { bestv[f][r] = d0v; bestk[f][r] = code; }
            }
        }
        sc2 = sqn;
    }

    // per-row argmin across the 16 code-classes; tie -> lower k
#pragma unroll
    for (int f = 0; f < 4; ++f)
#pragma unroll
        for (int r = 0; r < 4; ++r) {
            float v = bestv[f][r];
            int   k = bestk[f][r];
#pragma unroll
            for (int d = 1; d < 16; d <<= 1) {
                const float ov = __shfl_xor(v, d);
                const int   ok = __shfl_xor(k, d);
                if (ov < v || (ov == v && ok < k)) { v = ov; k = ok; }
            }
            if (m == 0) {
                const int row = rowb + f * 16 + q * 4 + r;
                mv[wg][row] = v;
                mk[wg][row] = k;
            }
        }
    __syncthreads();

    // merge 4 code-groups (ascending g, strict < keeps lower code), hist + loss
    if (t < 128) {
        float v = mv[0][t]; int k = mk[0][t];
#pragma unroll
        for (int g2 = 1; g2 < 4; ++g2) {
            const float vg = mv[g2][t];
            const int   kg = mk[g2][t];
            if (vg < v) { v = vg; k = kg; }
        }
        codeL[t] = k;
        atomicAdd(&counts[k], 1);
        float lp = xsqL[t] + v;       // ||x - c||^2
#pragma unroll
        for (int off = 32; off > 0; off >>= 1) lp += __shfl_down(lp, off);
        if ((t & 63) == 0) wsum[t >> 6] = lp;
    }
    __syncthreads();                  // codeL ready; all waves past the loop
    if (t == 0) atomicAdd(loss_accum, wsum[0] + wsum[1]);

    // ---- fused gather: four 32-row quarters through Q[32][257] (fp32, in arena)
    float* Q = (float*)Arena;
#pragma unroll
    for (int h = 0; h < 4; ++h) {
        {   // stage 32 cb rows (cb L2-hot: reused across all blocks)
            const int r = t & 31, seg = t >> 5;   // 16 segments x 16 c
            const float* src = cb + (size_t)codeL[h * 32 + r] * 256 + seg * 16;
#pragma unroll
            for (int i = 0; i < 4; ++i)
                *(f32x4*)&Q[r * 257 + seg * 16 + i * 4] = *(const f32x4*)(src + i * 4);
        }
        __syncthreads();
        {   // transpose write: 128B-contiguous fp32 runs per c
            const int hw4 = (t & 7) * 4;
            const int c0 = t >> 3;                // 0..63
            float* dst = out + (size_t)batch * 262144 + hwb + h * 32 + hw4;
#pragma unroll
            for (int i = 0; i < 4; ++i) {
                const int c = c0 + i * 64;
                f32x4 v;
                v[0] = Q[(hw4 + 0) * 257 + c];
                v[1] = Q[(hw4 + 1) * 257 + c];
                v[2] = Q[(hw4 + 2) * 257 + c];
                v[3] = Q[(hw4 + 3) * 257 + c];
                *(f32x4*)(dst + (size_t)c * 1024) = v;
            }
        }
        if (h < 3) __syncthreads();   // before overwriting Q for next quarter
    }
}

// ---- finalize: perplexity + loss scalar outputs (counts complete: kernel boundary)
__global__ __launch_bounds__(256) void finalize_kernel(
    const int* __restrict__ counts, const float* __restrict__ loss_accum,
    float* __restrict__ out)
{
    __shared__ float wsum[4];
    const int t = threadIdx.x;
    float s = 0.f;
#pragma unroll
    for (int mm = 0; mm < 4; ++mm) {
        const float p = (float)counts[t + 256 * mm] * (1.f / 32768.f);
        s += p * logf(p + 1e-10f);
    }
#pragma unroll
    for (int off = 32; off > 0; off >>= 1) s += __shfl_down(s, off);
    if ((t & 63) == 0) wsum[t >> 6] = s;
    __syncthreads();
    if (t == 0) {
        out[OUT_ELEMS]     = loss_accum[0] * (1.25f / 8388608.f);
        out[OUT_ELEMS + 1] = expf(-(wsum[0] + wsum[1] + wsum[2] + wsum[3]));
    }
}

extern "C" void kernel_launch(void* const* d_in, const int* in_sizes, int n_in,
                              void* d_out, int out_size, void* d_ws, size_t ws_size,
                              hipStream_t stream) {
    const float* x  = (const float*)d_in[0];
    const float* cb = (const float*)d_in[1];
    float* out = (float*)d_out;
    char* wsb = (char*)d_ws;
    int*            counts = (int*)(wsb + 0);
    float*          loss   = (float*)(wsb + 4096);
    float*          sq     = (float*)(wsb + 8192);
    unsigned short* chs    = (unsigned short*)(wsb + 16384);

    prep_kernel<<<64, 256, 0, stream>>>(cb, chs, sq, counts, loss);
    vq_kernel<<<256, 512, 0, stream>>>(x, cb, chs, sq, counts, loss, out);
    finalize_kernel<<<1, 256, 0, stream>>>(counts, loss, out);
}

// Round 9
// 127.791 us; speedup vs baseline: 1.0543x; 1.0543x over previous
//
#include <hip/hip_runtime.h>
#include <hip/hip_fp16.h>

typedef _Float16 half8 __attribute__((ext_vector_type(8)));
typedef _Float16 half4v __attribute__((ext_vector_type(4)));
typedef __attribute__((ext_vector_type(4))) float f32x4;

#define OUT_ELEMS 8388608

// ws layout (bytes):
// 0      counts int[1024]        (zeroed by prep block 0)
// 4096   loss   float            (zeroed by prep)
// 8192   sq     float[1024]
// 16384  chs    ushort[1024*256] (fp16 of 1024*cb, FRAGMENT-PACKED, see below)
//
// chs packed layout (16B chunks): [g:4][s:16][ks:8][m:16][q:4]
//   code = g*256 + s*16 + m; chunk (ks,q) = halfs [ks*32+q*8, +8) of that row.
// B-fragment read: wave of code-group g, stage s, lane(m=lane&15,q=lane>>4),
// frag ks reads chunk ((g*16+s)*8+ks)*64 + m*4 + q  -> per wave instruction
// (fixed ks) the 64 lanes cover ONE contiguous 1KB block. chs is 512KB,
// L2-resident. Main loop: no LDS, no barriers, no inline asm.

// ---- prep: zero accumulators + codebook -> fp16*1024 packed + ||c||^2 ----
__global__ __launch_bounds__(256) void prep_kernel(const float* __restrict__ cb,
        unsigned short* __restrict__ chs, float* __restrict__ sq,
        int* __restrict__ counts, float* __restrict__ loss) {
    const int t = threadIdx.x;
    if (blockIdx.x == 0) {
        ((int4*)counts)[t] = make_int4(0, 0, 0, 0);
        if (t == 0) *loss = 0.f;
    }
    const int row = blockIdx.x * 16 + (t >> 4);   // code index 0..1023
    const int d0 = (t & 15) * 16;
    const float* src = cb + row * 256 + d0;
    half8 h0, h1;
    float s = 0.f;
#pragma unroll
    for (int i = 0; i < 16; ++i) {
        const float v = src[i];
        s += v * v;
        const _Float16 h = (_Float16)(v * 1024.f);
        if (i < 8) h0[i] = h; else h1[i - 8] = h;
    }
    // packed write: j0=(t&15)*2 (even) -> chunks (ks, qq) and (ks, qq+1), contiguous
    const int g = row >> 8, st = (row >> 4) & 15, m = row & 15;
    const int j0 = (t & 15) * 2;
    const int ks = j0 >> 2, qq = j0 & 3;
    unsigned short* dst = chs + (size_t)((((g * 16 + st) * 8 + ks) * 64) + m * 4 + qq) * 8;
    *(half8*)dst       = h0;
    *(half8*)(dst + 8) = h1;
#pragma unroll
    for (int off = 1; off < 16; off <<= 1) s += __shfl_xor(s, off);
    if ((t & 15) == 0) sq[row] = s;
}

// ---- fused vq: grid 512 (2/CU RESIDENT), 512 thr = 8 waves
//      = 4 code-groups x 2 row-groups; 64 rows/block, M=32/wave.
// 16 waves/CU (4/SIMD) hide the L2 latency of the coalesced B stream.
__global__ __launch_bounds__(512, 4) void vq_kernel(
    const float* __restrict__ x, const float* __restrict__ cb,
    const unsigned short* __restrict__ chs, const float* __restrict__ sq,
    int* __restrict__ counts, float* __restrict__ loss_accum,
    float* __restrict__ out)
{
    __shared__ __align__(16) unsigned char Arena[33024]; // XL(32K) -> Q[32][257](32.9K)
    __shared__ float mv[4][64];
    __shared__ int   mk[4][64];
    __shared__ float xsqL[64];
    __shared__ int   codeL[64];

    const int t = threadIdx.x;
    const int lane = t & 63;
    const int w  = t >> 6;
    const int wg = w >> 1;            // code group 0..3 (256 codes each)
    const int wl = w & 1;             // row group 0..1 (32 rows each)
    const int m = lane & 15;
    const int q = lane >> 4;
    const int kb = wg << 8;
    const int rowb = wl << 5;
    const int bid = blockIdx.x;
    const int batch = bid >> 4;
    const int hwb = (bid & 15) << 6;  // 64 hw rows per block

    // ---- x staging: fp32 [c][hw] (coalesced, NT) -> fp16 [hw:64][c:256] LDS, swizzled
    // 8B-group swizzle e(hw) = ((hw&7) ^ ((hw>>3)&7)) << 1 (even keeps 16B pairs).
    unsigned short* XL = (unsigned short*)Arena;
    {
        const float* xg = x + (size_t)batch * 262144 + hwb;
#pragma unroll
        for (int p = 0; p < 2; ++p) {
            const int id = p * 512 + t;
            const int c4 = id >> 4;       // 0..63 (c-group of 4)
            const int hw4 = id & 15;      // 0..15 (hw-group of 4)
            const float* s0 = xg + (size_t)(c4 * 4) * 1024 + hw4 * 4;
            const f32x4 v0 = __builtin_nontemporal_load((const f32x4*)(s0));
            const f32x4 v1 = __builtin_nontemporal_load((const f32x4*)(s0 + 1024));
            const f32x4 v2 = __builtin_nontemporal_load((const f32x4*)(s0 + 2048));
            const f32x4 v3 = __builtin_nontemporal_load((const f32x4*)(s0 + 3072));
#pragma unroll
            for (int j = 0; j < 4; ++j) {
                const int hw = hw4 * 4 + j;
                const int e = (((hw & 7) ^ ((hw >> 3) & 7)) << 1);
                half4v hv;
                hv[0] = (_Float16)v0[j];
                hv[1] = (_Float16)v1[j];
                hv[2] = (_Float16)v2[j];
                hv[3] = (_Float16)v3[j];
                *(half4v*)(XL + hw * 256 + ((c4 ^ e) << 2)) = hv;
            }
        }
    }
    __syncthreads();

    // ---- A frags from LDS (conflict-free b128); fused ||x||^2 (fp16 path)
    half8 Ah[2][8];
#pragma unroll
    for (int f = 0; f < 2; ++f) {
        const int hw = rowb + f * 16 + m;
        const unsigned short* row = XL + hw * 256;
        const int e = (((hw & 7) ^ ((hw >> 3) & 7)) << 1);
        float xs = 0.f;
#pragma unroll
        for (int ks = 0; ks < 8; ++ks) {
            const half8 a = *(const half8*)(row + (((8 * ks + 2 * q) ^ e) << 2));
            Ah[f][ks] = a;
#pragma unroll
            for (int j = 0; j < 8; ++j) { const float fv = (float)a[j]; xs = fmaf(fv, fv, xs); }
        }
        xs += __shfl_xor(xs, 16);
        xs += __shfl_xor(xs, 32);
        if (wg == 0 && q == 0) xsqL[hw] = xs;
    }
    // NO barrier: XL is only overwritten by gather (after two later barriers).

    float bestv[2][4];
#pragma unroll
    for (int f = 0; f < 2; ++f)
#pragma unroll
        for (int r = 0; r < 4; ++r) bestv[f][r] = 3.4e38f;
    unsigned int bests = 0u;          // 8x 4-bit stage-of-best (f*4+r nibbles)

    // per-lane packed-B base (halfs): group block 65536, stage block 4096
    const unsigned short* bbase = chs + (size_t)wg * 65536 + (m * 4 + q) * 8;

    for (int s = 0; s < 16; ++s) {    // 16 codes per stage per group
        const unsigned short* bp = bbase + s * 4096;
        half8 Bf[8];
#pragma unroll
        for (int ks = 0; ks < 8; ++ks)
            Bf[ks] = *(const half8*)(bp + ks * 512);   // 1KB/wave-instr, contiguous
        const float sc2 = sq[kb + s * 16 + m];
        f32x4 a0 = {0.f,0.f,0.f,0.f}, a1 = {0.f,0.f,0.f,0.f};
#pragma unroll
        for (int ks = 0; ks < 8; ++ks) {
            a0 = __builtin_amdgcn_mfma_f32_16x16x32_f16(Ah[0][ks], Bf[ks], a0, 0, 0, 0);
            a1 = __builtin_amdgcn_mfma_f32_16x16x32_f16(Ah[1][ks], Bf[ks], a1, 0, 0, 0);
        }
#pragma unroll
        for (int f = 0; f < 2; ++f) {
            const f32x4 a = f ? a1 : a0;
#pragma unroll
            for (int r = 0; r < 4; ++r) {
                const float d0v = fmaf(-0.001953125f, a[r], sc2);  // -2/1024 undoes B scale
                const int sh = (f * 4 + r) * 4;
                if (d0v < bestv[f][r]) {
                    bestv[f][r] = d0v;
                    bests = (bests & ~(15u << sh)) | ((unsigned)s << sh);
                }
            }
        }
    }

    // per-row argmin across the 16 code-classes; tie -> lower k
#pragma unroll
    for (int f = 0; f < 2; ++f)
#pragma unroll
        for (int r = 0; r < 4; ++r) {
            float v = bestv[f][r];
            int   k = kb + (int)((bests >> ((f * 4 + r) * 4)) & 15u) * 16 + m;
#pragma unroll
            for (int d = 1; d < 16; d <<= 1) {
                const float ov = __shfl_xor(v, d);
                const int   ok = __shfl_xor(k, d);
                if (ov < v || (ov == v && ok < k)) { v = ov; k = ok; }
            }
            if (m == 0) {
                const int row = rowb + f * 16 + q * 4 + r;
                mv[wg][row] = v;
                mk[wg][row] = k;
            }
        }
    __syncthreads();

    // merge 4 code-groups (ascending g, strict < keeps lower code), hist + loss
    if (t < 64) {
        float v = mv[0][t]; int k = mk[0][t];
#pragma unroll
        for (int g2 = 1; g2 < 4; ++g2) {
            const float vg = mv[g2][t];
            const int   kg = mk[g2][t];
            if (vg < v) { v = vg; k = kg; }
        }
        codeL[t] = k;
        atomicAdd(&counts[k], 1);
        float lp = xsqL[t] + v;       // ||x - c||^2
#pragma unroll
        for (int off = 32; off > 0; off >>= 1) lp += __shfl_down(lp, off);
        if (t == 0) atomicAdd(loss_accum, lp);
    }
    __syncthreads();                  // codeL ready; all waves past the loop

    // ---- fused gather: two 32-row halves through Q[32][257] (fp32, in arena)
    float* Q = (float*)Arena;
#pragma unroll
    for (int h = 0; h < 2; ++h) {
        {   // stage 32 cb rows (cb L2-hot: reused across all blocks)
            const int r = t & 31, seg = t >> 5;   // 16 segments x 16 c
            const float* src = cb + (size_t)codeL[h * 32 + r] * 256 + seg * 16;
#pragma unroll
            for (int i = 0; i < 4; ++i)
                *(f32x4*)&Q[r * 257 + seg * 16 + i * 4] = *(const f32x4*)(src + i * 4);
        }
        __syncthreads();
        {   // transpose write: 128B-contiguous fp32 runs per c (NT: don't evict chs)
            const int hw4 = (t & 7) * 4;
            const int c0 = t >> 3;                // 0..63
            float* dst = out + (size_t)batch * 262144 + hwb + h * 32 + hw4;
#pragma unroll
            for (int i = 0; i < 4; ++i) {
                const int c = c0 + i * 64;
                f32x4 v;
                v[0] = Q[(hw4 + 0) * 257 + c];
                v[1] = Q[(hw4 + 1) * 257 + c];
                v[2] = Q[(hw4 + 2) * 257 + c];
                v[3] = Q[(hw4 + 3) * 257 + c];
                __builtin_nontemporal_store(v, (f32x4*)(dst + (size_t)c * 1024));
            }
        }
        if (h == 0) __syncthreads();  // before overwriting Q for half 1
    }
}

// ---- finalize: perplexity + loss scalar outputs (counts complete: kernel boundary)
__global__ __launch_bounds__(256) void finalize_kernel(
    const int* __restrict__ counts, const float* __restrict__ loss_accum,
    float* __restrict__ out)
{
    __shared__ float wsum[4];
    const int t = threadIdx.x;
    float s = 0.f;
#pragma unroll
    for (int mm = 0; mm < 4; ++mm) {
        const float p = (float)counts[t + 256 * mm] * (1.f / 32768.f);
        s += p * logf(p + 1e-10f);
    }
#pragma unroll
    for (int off = 32; off > 0; off >>= 1) s += __shfl_down(s, off);
    if ((t & 63) == 0) wsum[t >> 6] = s;
    __syncthreads();
    if (t == 0) {
        out[OUT_ELEMS]     = loss_accum[0] * (1.25f / 8388608.f);
        out[OUT_ELEMS + 1] = expf(-(wsum[0] + wsum[1] + wsum[2] + wsum[3]));
    }
}

extern "C" void kernel_launch(void* const* d_in, const int* in_sizes, int n_in,
                              void* d_out, int out_size, void* d_ws, size_t ws_size,
                              hipStream_t stream) {
    const float* x  = (const float*)d_in[0];
    const float* cb = (const float*)d_in[1];
    float* out = (float*)d_out;
    char* wsb = (char*)d_ws;
    int*            counts = (int*)(wsb + 0);
    float*          loss   = (float*)(wsb + 4096);
    float*          sq     = (float*)(wsb + 8192);
    unsigned short* chs    = (unsigned short*)(wsb + 16384);

    prep_kernel<<<64, 256, 0, stream>>>(cb, chs, sq, counts, loss);
    vq_kernel<<<512, 512, 0, stream>>>(x, cb, chs, sq, counts, loss, out);
    finalize_kernel<<<1, 256, 0, stream>>>(counts, loss, out);
}